// Round 7
// baseline (259.121 us; speedup 1.0000x reference)
//
#include <hip/hip_runtime.h>

// B=8, H=W=48 -> 2304 positions, C=256 channels.
// raw[b,ij,kl] = sum_c A[b,ij,c]*B[b,kl,c]
// out = raw / sqrt(sum_ij raw^2)     (reference's 1/C cancels in the norm)
//
// R9: single-GEMM, sync-free. R8's persistent/spin design measured 3.2%
// MfmaUtil -- 97% wait (grid-capped 2 blocks/CU + serialized group sync).
// R8's profile also showed the fills are OUTSIDE the timed window: R2's
// 237 us = cvt(15) + P1(~105) + P2(~105). So we keep the single-GEMM idea
// but with zero inter-block sync:
//   1. convert: fp32->bf16 + zero colSqG
//   2. corr_raw: EXACT R2 GEMM structure (2592 blocks, 4/CU, proven);
//      epilogue stores the RAW tile to out and atomicAdds colSq
//   3. normalize: in-place out *= rsqrt(colSq[col]) -- pure BW (~60 us),
//      replaces the ~105 us recompute pass.
// fp32 raw round-trips through HBM exactly -> arithmetic identical to R2.

#define HW2 2304
#define CH  256
#define NB  8
#define NELEM (NB * HW2 * CH)   // 4,718,592 per input

typedef __attribute__((ext_vector_type(8))) short bf16x8;   // 8 bf16 = 4 VGPRs
typedef __attribute__((ext_vector_type(4))) float f32x4;    // MFMA acc

static __device__ inline unsigned short f2bf(float f) {
    union { float f; unsigned u; } x; x.f = f;
    unsigned r = x.u + 0x7FFFu + ((x.u >> 16) & 1u);
    return (unsigned short)(r >> 16);
}

// async global->LDS, 16B per lane (global_load_lds_dwordx4)
static __device__ inline void async_copy16(const void* g, void* l) {
    __builtin_amdgcn_global_load_lds(
        (const __attribute__((address_space(1))) unsigned int*)g,
        (__attribute__((address_space(3))) unsigned int*)l, 16, 0, 0);
}

// ---------------------------------------------------------------------------
// 1. convert: fp32 -> bf16 (A,B row-major) + zero colSqG.
// ---------------------------------------------------------------------------
__global__ __launch_bounds__(256) void convert_bf16(const float* __restrict__ A,
                                                    const float* __restrict__ B,
                                                    unsigned short* __restrict__ Abf,
                                                    unsigned short* __restrict__ Bbf,
                                                    float* __restrict__ colSqG) {
    const int gidx = blockIdx.x * blockDim.x + threadIdx.x;
    if (gidx < NB * HW2) colSqG[gidx] = 0.0f;     // 18432 floats
    const int n4 = NELEM / 4;
    for (int i = gidx; i < 2 * n4; i += gridDim.x * blockDim.x) {
        const bool isA = i < n4;
        const int j = isA ? i : i - n4;
        float4 v = (isA ? (const float4*)A : (const float4*)B)[j];
        ushort4 p;
        p.x = f2bf(v.x); p.y = f2bf(v.y); p.z = f2bf(v.z); p.w = f2bf(v.w);
        *(ushort4*)((isA ? Abf : Bbf) + (size_t)j * 4) = p;
    }
}

// ---------------------------------------------------------------------------
// 2. corr_raw: R2's proven GEMM (128x128 tile, two 32-k chunks per barrier
//    pair, XCD swizzle, 4 blocks/CU). Epilogue: colSq atomics + RAW store.
// ---------------------------------------------------------------------------
__global__ __launch_bounds__(256) void corr_raw(const unsigned short* __restrict__ Abf,
                                                const unsigned short* __restrict__ Bbf,
                                                float* __restrict__ colSqG,
                                                float* __restrict__ out) {
    __shared__ unsigned short As[2 * 128 * 32];   // 16 KB
    __shared__ unsigned short Bs[2 * 128 * 32];   // 16 KB
    __shared__ float colSq[128];

    const int tid = threadIdx.x;

    // XCD swizzle: batch fastest-varying -> each XCD works ~one batch (L2-fit)
    const int lin = blockIdx.x + 18 * (blockIdx.y + 18 * blockIdx.z);
    const int b  = lin & 7;
    const int r_ = lin >> 3;          // 0..323
    const int bx = r_ % 18;           // column tile (kl)
    const int by = r_ / 18;           // row tile (ij)

    if (tid < 128) colSq[tid] = 0.0f;

    const unsigned short* Ab = Abf + ((size_t)b * HW2 + (size_t)by * 128) * CH;
    const unsigned short* Bb = Bbf + ((size_t)b * HW2 + (size_t)bx * 128) * CH;

    const int srow  = tid >> 2;
    const int skcol = (tid & 3) * 8;
    const int wave = tid >> 6, lane = tid & 63;
    const int wm = (wave >> 1) * 64, wn = (wave & 1) * 64;
    const int lr = lane & 15, quad = lane >> 4, k8 = quad * 8;

    f32x4 acc[4][4];
#pragma unroll
    for (int i = 0; i < 4; i++)
#pragma unroll
        for (int j = 0; j < 4; j++) acc[i][j] = (f32x4){0.f, 0.f, 0.f, 0.f};

    for (int kt = 0; kt < CH; kt += 64) {
#pragma unroll
        for (int c = 0; c < 2; c++) {
            const int kof = kt + c * 32;
#pragma unroll
            for (int i = 0; i < 2; i++) {
                async_copy16(Ab + (size_t)(srow + i * 64) * CH + kof + skcol,
                             &As[c * 4096 + tid * 8 + i * 2048]);
                async_copy16(Bb + (size_t)(srow + i * 64) * CH + kof + skcol,
                             &Bs[c * 4096 + tid * 8 + i * 2048]);
            }
        }
        __syncthreads();   // vmcnt(0) drain + barrier
#pragma unroll
        for (int c = 0; c < 2; c++) {
            bf16x8 af[4], bfr[4];
#pragma unroll
            for (int mt = 0; mt < 4; mt++)
                af[mt] = *(const bf16x8*)&As[c * 4096 + (wm + mt * 16 + lr) * 32 + k8];
#pragma unroll
            for (int nt = 0; nt < 4; nt++)
                bfr[nt] = *(const bf16x8*)&Bs[c * 4096 + (wn + nt * 16 + lr) * 32 + k8];
#pragma unroll
            for (int mt = 0; mt < 4; mt++)
#pragma unroll
                for (int nt = 0; nt < 4; nt++)
                    acc[mt][nt] = __builtin_amdgcn_mfma_f32_16x16x32_bf16(
                        af[mt], bfr[nt], acc[mt][nt], 0, 0, 0);
        }
        __syncthreads();
    }

    // ---- raw tile store (unnormalized) ----
    const size_t outBase = (size_t)b * HW2 * HW2;
#pragma unroll
    for (int nt = 0; nt < 4; nt++) {
        const int col = bx * 128 + wn + nt * 16 + lr;
#pragma unroll
        for (int mt = 0; mt < 4; mt++) {
            const int row0 = by * 128 + wm + mt * 16 + quad * 4;
            f32x4 v = acc[mt][nt];
#pragma unroll
            for (int r = 0; r < 4; r++)
                out[outBase + (size_t)(row0 + r) * HW2 + col] = v[r];
        }
    }

    // ---- per-column sum of squares -> LDS -> one global atomic per column
#pragma unroll
    for (int nt = 0; nt < 4; nt++) {
        float s = 0.f;
#pragma unroll
        for (int mt = 0; mt < 4; mt++) {
            f32x4 v = acc[mt][nt];
#pragma unroll
            for (int r = 0; r < 4; r++) s += v[r] * v[r];
        }
        s += __shfl_xor(s, 16);
        s += __shfl_xor(s, 32);
        if (quad == 0) atomicAdd(&colSq[wn + nt * 16 + lr], s);
    }
    __syncthreads();
    if (tid < 128)
        atomicAdd(&colSqG[(size_t)b * HW2 + bx * 128 + tid], colSq[tid]);
}

// ---------------------------------------------------------------------------
// 3. normalize: out *= rsqrt(colSq[b,col]), in place. Pure streaming.
//    col is float4-aligned (HW2 % 4 == 0) -> vector loads on both arrays.
// ---------------------------------------------------------------------------
__global__ __launch_bounds__(256) void normalize(float* __restrict__ out,
                                                 const float* __restrict__ colSqG) {
    const int total = NB * HW2 * (HW2 / 4);        // 10,616,832 float4s
    for (int i = blockIdx.x * blockDim.x + threadIdx.x; i < total;
         i += gridDim.x * blockDim.x) {
        float4 v = ((const float4*)out)[i];
        const int e   = i * 4;                      // fits: < 2^31 per batch slab? e up to 42.5M, ok
        const int col = e % HW2;                    // float4-aligned
        const int b   = i / (HW2 * (HW2 / 4));
        float4 c = *(const float4*)(colSqG + b * HW2 + col);
        v.x *= rsqrtf(c.x);
        v.y *= rsqrtf(c.y);
        v.z *= rsqrtf(c.z);
        v.w *= rsqrtf(c.w);
        ((float4*)out)[i] = v;
    }
}

extern "C" void kernel_launch(void* const* d_in, const int* in_sizes, int n_in,
                              void* d_out, int out_size, void* d_ws, size_t ws_size,
                              hipStream_t stream) {
    const float* A = (const float*)d_in[0];
    const float* B = (const float*)d_in[1];
    float* out = (float*)d_out;

    unsigned short* Abf = (unsigned short*)d_ws;           // NELEM bf16
    unsigned short* Bbf = Abf + NELEM;                     // NELEM bf16
    float* colSqG = (float*)(Bbf + NELEM);                 // NB*HW2 f32 (16B-aligned)

    convert_bf16<<<2048, 256, 0, stream>>>(A, B, Abf, Bbf, colSqG);

    dim3 grid(HW2 / 128, HW2 / 128, NB);   // 18 x 18 x 8 = 2592 blocks
    corr_raw<<<grid, 256, 0, stream>>>(Abf, Bbf, colSqG, out);

    normalize<<<2048, 256, 0, stream>>>(out, colSqG);
}

// Round 8
// 240.141 us; speedup vs baseline: 1.0790x; 1.0790x over previous
//
#include <hip/hip_runtime.h>

// B=8, H=W=48 -> 2304 positions, C=256 channels.
// raw[b,ij,kl] = sum_c A[b,ij,c]*B[b,kl,c]
// out = raw / sqrt(sum_ij raw^2)     (reference's 1/C cancels in the norm)
//
// R10: budget model (fits R2-R9 within ~5us): fill ~100 (in-window, fixed)
// + cvt 15 + P1 35 + P2 87 (of which ~52 is the scalar-store epilogue).
//   - corr_norm: champion GEMM + LDS-transposed float4 epilogue (write ~28us)
//   - P1 replaced by Gram chain sized for occupancy: gram_part 768 blocks
//     (K-split x6, plain partial-slab stores), g2bf_sum, colsq (R5 verbatim)
// 5 dispatches, no atomics, no memsets.

#define HW2 2304
#define CH  256
#define NB  8
#define NELEM (NB * HW2 * CH)   // 4,718,592 per input
#define KSG 6                   // gram K-split: 2304/6 = 384 = 6 x 64

typedef __attribute__((ext_vector_type(8))) short bf16x8;   // 8 bf16 = 4 VGPRs
typedef __attribute__((ext_vector_type(4))) float f32x4;    // MFMA acc

static __device__ inline unsigned short f2bf(float f) {
    union { float f; unsigned u; } x; x.f = f;
    unsigned r = x.u + 0x7FFFu + ((x.u >> 16) & 1u);
    return (unsigned short)(r >> 16);
}

static __device__ inline float bf2f(unsigned short u) {
    union { unsigned u; float f; } x; x.u = ((unsigned)u) << 16;
    return x.f;
}

// async global->LDS, 16B per lane (global_load_lds_dwordx4)
static __device__ inline void async_copy16(const void* g, void* l) {
    __builtin_amdgcn_global_load_lds(
        (const __attribute__((address_space(1))) unsigned int*)g,
        (__attribute__((address_space(3))) unsigned int*)l, 16, 0, 0);
}

// ---------------------------------------------------------------------------
// 1. convert: A,B fp32 -> bf16 row-major; additionally A^T (c-major) for gram.
//    (R5 verbatim -- verified.)
// ---------------------------------------------------------------------------
__global__ __launch_bounds__(256) void convert_bf16(const float* __restrict__ A,
                                                    const float* __restrict__ B,
                                                    unsigned short* __restrict__ Abf,
                                                    unsigned short* __restrict__ Bbf,
                                                    unsigned short* __restrict__ Atbf) {
    __shared__ unsigned short t[64][65];   // +1 pad breaks transpose bank conflicts
    const int blk = blockIdx.x;            // 0..2303
    const bool isA = blk < 1152;
    const int tb = isA ? blk : blk - 1152;
    const int b  = tb / 144;               // 144 tiles per batch = 36 ij x 4 c
    const int tt = tb % 144;
    const int ijt = tt >> 2, ct = tt & 3;
    const size_t base = ((size_t)b * HW2 + (size_t)ijt * 64) * CH + ct * 64;
    const float* src = (isA ? A : B) + base;
    unsigned short* dst = (isA ? Abf : Bbf) + base;
    const int tid = threadIdx.x;
    const int lr = tid & 15, rq = tid >> 4;
#pragma unroll
    for (int p = 0; p < 4; p++) {
        const int row = rq + p * 16;
        float4 v = *(const float4*)(src + (size_t)row * CH + lr * 4);
        ushort4 u;
        u.x = f2bf(v.x); u.y = f2bf(v.y); u.z = f2bf(v.z); u.w = f2bf(v.w);
        *(ushort4*)(dst + (size_t)row * CH + lr * 4) = u;
        if (isA) {
            t[row][lr * 4 + 0] = u.x; t[row][lr * 4 + 1] = u.y;
            t[row][lr * 4 + 2] = u.z; t[row][lr * 4 + 3] = u.w;
        }
    }
    if (isA) {
        __syncthreads();
#pragma unroll
        for (int p = 0; p < 4; p++) {
            const int c = rq + p * 16;     // channel = transposed row
            ushort4 u;
            u.x = t[lr * 4 + 0][c]; u.y = t[lr * 4 + 1][c];
            u.z = t[lr * 4 + 2][c]; u.w = t[lr * 4 + 3][c];
            *(ushort4*)(Atbf + ((size_t)b * CH + (size_t)(ct * 64 + c)) * HW2
                        + (size_t)ijt * 64 + lr * 4) = u;
        }
    }
}

// ---------------------------------------------------------------------------
// 2. gram_part: partial G = At(64 rows) . At(64 rows)^T over a 384-wide K
//    chunk. grid (4,4,NB*KSG) = 768 blocks (3/CU). Plain stores into per-ks
//    slabs -> no atomics, no memset.
// ---------------------------------------------------------------------------
__global__ __launch_bounds__(256) void gram_part(const unsigned short* __restrict__ Atbf,
                                                 float* __restrict__ Gp) {
    __shared__ unsigned short As[2][4096];   // [buf][c2*2048 + row*32 + k8]
    __shared__ unsigned short Bs[2][4096];
    const int tid = threadIdx.x;
    const int bx = blockIdx.x, by = blockIdx.y;
    const int b  = blockIdx.z / KSG, ks = blockIdx.z % KSG;
    const int kt0 = ks * (HW2 / KSG);
    const unsigned short* Ar = Atbf + ((size_t)b * CH + by * 64) * HW2;
    const unsigned short* Br = Atbf + ((size_t)b * CH + bx * 64) * HW2;
    const int srow = tid >> 2, skcol = (tid & 3) * 8;
    const int wave = tid >> 6, lane = tid & 63;
    const int wm = (wave >> 1) * 32, wn = (wave & 1) * 32;
    const int lr = lane & 15, quad = lane >> 4, k8 = quad * 8;

    f32x4 acc[2][2];
#pragma unroll
    for (int i = 0; i < 2; i++)
#pragma unroll
        for (int j = 0; j < 2; j++) acc[i][j] = (f32x4){0.f, 0.f, 0.f, 0.f};

#define G_STAGE(bufi, kt)                                                      \
    {                                                                          \
        _Pragma("unroll")                                                      \
        for (int c2 = 0; c2 < 2; c2++) {                                       \
            async_copy16(Ar + (size_t)srow * HW2 + (kt) + c2 * 32 + skcol,     \
                         &As[bufi][c2 * 2048 + tid * 8]);                      \
            async_copy16(Br + (size_t)srow * HW2 + (kt) + c2 * 32 + skcol,     \
                         &Bs[bufi][c2 * 2048 + tid * 8]);                      \
        }                                                                      \
    }

    G_STAGE(0, kt0);
    __syncthreads();
    for (int t = 0; t < 6; t++) {
        const int buf = t & 1;
        if (t < 5) G_STAGE(buf ^ 1, kt0 + (t + 1) * 64);
#pragma unroll
        for (int c2 = 0; c2 < 2; c2++) {
            bf16x8 af[2], bfr[2];
#pragma unroll
            for (int mt = 0; mt < 2; mt++)
                af[mt] = *(const bf16x8*)&As[buf][c2 * 2048 + (wm + mt * 16 + lr) * 32 + k8];
#pragma unroll
            for (int nt = 0; nt < 2; nt++)
                bfr[nt] = *(const bf16x8*)&Bs[buf][c2 * 2048 + (wn + nt * 16 + lr) * 32 + k8];
#pragma unroll
            for (int mt = 0; mt < 2; mt++)
#pragma unroll
                for (int nt = 0; nt < 2; nt++)
                    acc[mt][nt] = __builtin_amdgcn_mfma_f32_16x16x32_bf16(
                        af[mt], bfr[nt], acc[mt][nt], 0, 0, 0);
        }
        __syncthreads();
    }
    float* Gpb = Gp + ((size_t)(ks * NB + b)) * (CH * CH);
#pragma unroll
    for (int mt = 0; mt < 2; mt++)
#pragma unroll
        for (int nt = 0; nt < 2; nt++) {
            const int row = by * 64 + wm + mt * 16 + quad * 4;
            const int col = bx * 64 + wn + nt * 16 + lr;
#pragma unroll
            for (int r = 0; r < 4; r++)
                Gpb[(size_t)(row + r) * CH + col] = acc[mt][nt][r];
        }
}

// ---------------------------------------------------------------------------
// 3. g2bf_sum: Gbf = bf16( sum_ks Gp[ks] ).  131072 threads x float4.
// ---------------------------------------------------------------------------
__global__ __launch_bounds__(256) void g2bf_sum(const float* __restrict__ Gp,
                                                unsigned short* __restrict__ Gbf) {
    const int f = blockIdx.x * 256 + threadIdx.x;    // 0..131071 float4s
    float4 s = {0.f, 0.f, 0.f, 0.f};
#pragma unroll
    for (int ks = 0; ks < KSG; ks++) {
        float4 v = ((const float4*)(Gp + (size_t)ks * NB * CH * CH))[f];
        s.x += v.x; s.y += v.y; s.z += v.z; s.w += v.w;
    }
    ushort4 u;
    u.x = f2bf(s.x); u.y = f2bf(s.y); u.z = f2bf(s.z); u.w = f2bf(s.w);
    ((ushort4*)Gbf)[f] = u;
}

// ---------------------------------------------------------------------------
// 4. colsq (R5 verbatim -- verified): M = B.G, colSq[kl] = sum_c' M*B.
//    grid (2,36,8) = 576 blocks; slabs cs0/cs1 summed at use.
// ---------------------------------------------------------------------------
__global__ __launch_bounds__(256) void colsq(const unsigned short* __restrict__ Bbf,
                                             const unsigned short* __restrict__ Gbf,
                                             float* __restrict__ cs0,
                                             float* __restrict__ cs1) {
    __shared__ unsigned short As[2][4096];   // B-tile: 64 rows x 64k
    __shared__ unsigned short Bs[2][8192];   // G-tile: 128 rows x 64k
    __shared__ float colSqL[64];
    const int tid = threadIdx.x;
    const int bx = blockIdx.x;   // c' half (0/1)
    const int by = blockIdx.y;   // kl tile of 64
    const int b  = blockIdx.z;
    const unsigned short* Ab = Bbf + ((size_t)b * HW2 + by * 64) * CH;
    const unsigned short* Gb = Gbf + ((size_t)b * CH + bx * 128) * CH;
    const int srow = tid >> 2, skcol = (tid & 3) * 8;
    const int wave = tid >> 6, lane = tid & 63;
    const int wm = (wave >> 1) * 32, wn = (wave & 1) * 64;
    const int lr = lane & 15, quad = lane >> 4, k8 = quad * 8;

    f32x4 acc[2][4];
#pragma unroll
    for (int i = 0; i < 2; i++)
#pragma unroll
        for (int j = 0; j < 4; j++) acc[i][j] = (f32x4){0.f, 0.f, 0.f, 0.f};

#define C_STAGE(bufi, kt)                                                      \
    {                                                                          \
        _Pragma("unroll")                                                      \
        for (int c2 = 0; c2 < 2; c2++) {                                       \
            async_copy16(Ab + (size_t)srow * CH + (kt) + c2 * 32 + skcol,      \
                         &As[bufi][c2 * 2048 + tid * 8]);                      \
            _Pragma("unroll")                                                  \
            for (int i = 0; i < 2; i++)                                        \
                async_copy16(Gb + (size_t)(srow + i * 64) * CH + (kt) + c2 * 32 + skcol, \
                             &Bs[bufi][c2 * 4096 + tid * 8 + i * 2048]);       \
        }                                                                      \
    }

    C_STAGE(0, 0);
    __syncthreads();
    for (int t = 0; t < 4; t++) {
        const int buf = t & 1;
        if (t < 3) C_STAGE(buf ^ 1, (t + 1) * 64);
#pragma unroll
        for (int c2 = 0; c2 < 2; c2++) {
            bf16x8 af[2], bfr[4];
#pragma unroll
            for (int mt = 0; mt < 2; mt++)
                af[mt] = *(const bf16x8*)&As[buf][c2 * 2048 + (wm + mt * 16 + lr) * 32 + k8];
#pragma unroll
            for (int nt = 0; nt < 4; nt++)
                bfr[nt] = *(const bf16x8*)&Bs[buf][c2 * 4096 + (wn + nt * 16 + lr) * 32 + k8];
#pragma unroll
            for (int mt = 0; mt < 2; mt++)
#pragma unroll
                for (int nt = 0; nt < 4; nt++)
                    acc[mt][nt] = __builtin_amdgcn_mfma_f32_16x16x32_bf16(
                        af[mt], bfr[nt], acc[mt][nt], 0, 0, 0);
        }
        __syncthreads();
    }

    if (tid < 64) colSqL[tid] = 0.f;
    __syncthreads();
#pragma unroll
    for (int mt = 0; mt < 2; mt++)
#pragma unroll
        for (int r = 0; r < 4; r++) {
            const int lrow = wm + mt * 16 + quad * 4 + r;   // 0..63
            float s = 0.f;
#pragma unroll
            for (int nt = 0; nt < 4; nt++) {
                const int col = bx * 128 + wn + nt * 16 + lr;
                s += acc[mt][nt][r] * bf2f(Ab[(size_t)lrow * CH + col]);
            }
            s += __shfl_xor(s, 1); s += __shfl_xor(s, 2);
            s += __shfl_xor(s, 4); s += __shfl_xor(s, 8);
            if (lr == 0) atomicAdd(&colSqL[lrow], s);   // LDS atomic, 2 waves/row
        }
    __syncthreads();
    if (tid < 64)
        (bx == 0 ? cs0 : cs1)[(size_t)b * HW2 + by * 64 + tid] = colSqL[tid];
}

// ---------------------------------------------------------------------------
// 5. corr_norm: champion GEMM (128x128, 2x32-k per barrier pair, XCD swizzle)
//    + NEW epilogue: LDS-transpose the fp32 tile (2 rounds of 64 rows) and
//    store float4-coalesced with rsqrt applied. Write BW ~3.3 -> ~6 TB/s.
// ---------------------------------------------------------------------------
__global__ __launch_bounds__(256) void corr_norm(const unsigned short* __restrict__ Abf,
                                                 const unsigned short* __restrict__ Bbf,
                                                 const float* __restrict__ cs0,
                                                 const float* __restrict__ cs1,
                                                 float* __restrict__ out) {
    // 33792 B: K-loop uses first 32768 as As/Bs; epilogue reuses all as T[64][132]
    __shared__ __align__(16) unsigned char smem[64 * 132 * 4];
    unsigned short* As = (unsigned short*)smem;      // [2*128*32] = 8192 shorts
    unsigned short* Bs = As + 8192;                  // [2*128*32]

    const int tid = threadIdx.x;

    // XCD swizzle: batch fastest-varying -> each XCD works ~one batch (L2-fit)
    const int lin = blockIdx.x + 18 * (blockIdx.y + 18 * blockIdx.z);
    const int b  = lin & 7;
    const int r_ = lin >> 3;          // 0..323
    const int bx = r_ % 18;           // column tile (kl)
    const int by = r_ / 18;           // row tile (ij)

    const unsigned short* Ab = Abf + ((size_t)b * HW2 + (size_t)by * 128) * CH;
    const unsigned short* Bb = Bbf + ((size_t)b * HW2 + (size_t)bx * 128) * CH;

    const int srow  = tid >> 2;
    const int skcol = (tid & 3) * 8;
    const int wave = tid >> 6, lane = tid & 63;
    const int wm = (wave >> 1) * 64, wn = (wave & 1) * 64;
    const int lr = lane & 15, quad = lane >> 4, k8 = quad * 8;

    f32x4 acc[4][4];
#pragma unroll
    for (int i = 0; i < 4; i++)
#pragma unroll
        for (int j = 0; j < 4; j++) acc[i][j] = (f32x4){0.f, 0.f, 0.f, 0.f};

    for (int kt = 0; kt < CH; kt += 64) {
#pragma unroll
        for (int c = 0; c < 2; c++) {
            const int kof = kt + c * 32;
#pragma unroll
            for (int i = 0; i < 2; i++) {
                async_copy16(Ab + (size_t)(srow + i * 64) * CH + kof + skcol,
                             &As[c * 4096 + tid * 8 + i * 2048]);
                async_copy16(Bb + (size_t)(srow + i * 64) * CH + kof + skcol,
                             &Bs[c * 4096 + tid * 8 + i * 2048]);
            }
        }
        __syncthreads();   // vmcnt(0) drain + barrier
#pragma unroll
        for (int c = 0; c < 2; c++) {
            bf16x8 af[4], bfr[4];
#pragma unroll
            for (int mt = 0; mt < 4; mt++)
                af[mt] = *(const bf16x8*)&As[c * 4096 + (wm + mt * 16 + lr) * 32 + k8];
#pragma unroll
            for (int nt = 0; nt < 4; nt++)
                bfr[nt] = *(const bf16x8*)&Bs[c * 4096 + (wn + nt * 16 + lr) * 32 + k8];
#pragma unroll
            for (int mt = 0; mt < 4; mt++)
#pragma unroll
                for (int nt = 0; nt < 4; nt++)
                    acc[mt][nt] = __builtin_amdgcn_mfma_f32_16x16x32_bf16(
                        af[mt], bfr[nt], acc[mt][nt], 0, 0, 0);
        }
        __syncthreads();
    }
    // after final barrier As/Bs are dead -> reuse as fp32 transpose buffer

    // per-thread rinv for its 4 output columns (same cols in both rounds)
    const int c4 = tid & 31;
    const int colG0 = bx * 128 + c4 * 4;
    float4 s0 = *(const float4*)(cs0 + (size_t)b * HW2 + colG0);
    float4 s1 = *(const float4*)(cs1 + (size_t)b * HW2 + colG0);
    float4 rv;
    rv.x = rsqrtf(s0.x + s1.x);
    rv.y = rsqrtf(s0.y + s1.y);
    rv.z = rsqrtf(s0.z + s1.z);
    rv.w = rsqrtf(s0.w + s1.w);

    float* T = (float*)smem;          // [64][132]
    const int rbase = tid >> 5;       // 0..7
    const size_t outBase = (size_t)b * HW2 * HW2;

#pragma unroll
    for (int p = 0; p < 2; p++) {
        if ((wave >> 1) == p) {       // producer waves for rows p*64..p*64+63
#pragma unroll
            for (int mt = 0; mt < 4; mt++)
#pragma unroll
                for (int nt = 0; nt < 4; nt++) {
                    f32x4 v = acc[mt][nt];
#pragma unroll
                    for (int r = 0; r < 4; r++)
                        T[(mt * 16 + quad * 4 + r) * 132 + wn + nt * 16 + lr] = v[r];
                }
        }
        __syncthreads();
#pragma unroll
        for (int k = 0; k < 8; k++) {
            const int row = rbase + 8 * k;                 // 0..63
            float4 v = *(const float4*)&T[row * 132 + c4 * 4];
            v.x *= rv.x; v.y *= rv.y; v.z *= rv.z; v.w *= rv.w;
            *(float4*)&out[outBase + (size_t)(by * 128 + p * 64 + row) * HW2 + colG0] = v;
        }
        __syncthreads();
    }
}

extern "C" void kernel_launch(void* const* d_in, const int* in_sizes, int n_in,
                              void* d_out, int out_size, void* d_ws, size_t ws_size,
                              hipStream_t stream) {
    const float* A = (const float*)d_in[0];
    const float* B = (const float*)d_in[1];
    float* out = (float*)d_out;

    unsigned short* Abf  = (unsigned short*)d_ws;          // NELEM bf16
    unsigned short* Bbf  = Abf + NELEM;                    // NELEM bf16
    unsigned short* Atbf = Bbf + NELEM;                    // NELEM bf16 (A^T)
    unsigned short* Gbf  = Atbf + NELEM;                   // 8*256*256 bf16
    float* Gp  = (float*)(Gbf + (size_t)NB * CH * CH);     // KSG*8*256*256 f32
    float* cs0 = Gp + (size_t)KSG * NB * CH * CH;          // 8*2304 f32
    float* cs1 = cs0 + (size_t)NB * HW2;                   // 8*2304 f32

    convert_bf16<<<2304, 256, 0, stream>>>(A, B, Abf, Bbf, Atbf);
    gram_part<<<dim3(4, 4, NB * KSG), 256, 0, stream>>>(Atbf, Gp);
    g2bf_sum<<<512, 256, 0, stream>>>(Gp, Gbf);
    colsq<<<dim3(2, 36, NB), 256, 0, stream>>>(Bbf, Gbf, cs0, cs1);

    dim3 grid(HW2 / 128, HW2 / 128, NB);   // 18 x 18 x 8 = 2592 blocks
    corr_norm<<<grid, 256, 0, stream>>>(Abf, Bbf, cs0, cs1, out);
}

// Round 9
// 237.968 us; speedup vs baseline: 1.0889x; 1.0091x over previous
//
#include <hip/hip_runtime.h>

// B=8, H=W=48 -> 2304 positions, C=256 channels.
// raw[b,ij,kl] = sum_c A[b,ij,c]*B[b,kl,c]
// out = raw / sqrt(sum_ij raw^2)     (reference's 1/C cancels in the norm)
//
// R11: R8's fused single-GEMM (passed, 236.8 -- best) with its one wasted
// knob fixed: PBLK 512 -> 1024. R8 ran 2 blocks/CU (half the CUs idle in
// the GEMM phase) yet tied the two-pass champion; measured resources
// (VGPR=68, LDS=33280) allow 4 blocks/CU co-resident = 1024 blocks.
// Tile mapping switched to group-major identity so a round-straddling
// group's missing members are the FIRST tiles of the next round (block 0's
// next tile completes the straddler) -> spin tails ~ one tile.
// Sync logic byte-identical to R8 (RMW-only, verified).

#define HW2 2304
#define CH  256
#define NB  8
#define NELEM (NB * HW2 * CH)   // 4,718,592 per input
#define NTILE 2592              // 18*18*8 tiles of 128x128
#define NGRP  144               // NB*18 column groups, 18 members each
#define PBLK  1024              // persistent blocks (4/CU, co-resident)

typedef __attribute__((ext_vector_type(8))) short bf16x8;   // 8 bf16 = 4 VGPRs
typedef __attribute__((ext_vector_type(4))) float f32x4;    // MFMA acc

static __device__ inline unsigned short f2bf(float f) {
    union { float f; unsigned u; } x; x.f = f;
    unsigned r = x.u + 0x7FFFu + ((x.u >> 16) & 1u);
    return (unsigned short)(r >> 16);
}

// async global->LDS, 16B per lane (global_load_lds_dwordx4)
static __device__ inline void async_copy16(const void* g, void* l) {
    __builtin_amdgcn_global_load_lds(
        (const __attribute__((address_space(1))) unsigned int*)g,
        (__attribute__((address_space(3))) unsigned int*)l, 16, 0, 0);
}

// ---------------------------------------------------------------------------
// 1. convert: fp32 -> bf16 (A,B row-major) + zero colSqG/cnt for this iter.
// ---------------------------------------------------------------------------
__global__ __launch_bounds__(256) void convert_bf16(const float* __restrict__ A,
                                                    const float* __restrict__ B,
                                                    unsigned short* __restrict__ Abf,
                                                    unsigned short* __restrict__ Bbf,
                                                    float* __restrict__ colSqG,
                                                    int* __restrict__ cnt) {
    const int gidx = blockIdx.x * blockDim.x + threadIdx.x;
    if (gidx < NB * HW2) colSqG[gidx] = 0.0f;     // 18432 floats
    if (gidx < NGRP) cnt[gidx] = 0;
    const int n4 = NELEM / 4;
    for (int i = gidx; i < 2 * n4; i += gridDim.x * blockDim.x) {
        const bool isA = i < n4;
        const int j = isA ? i : i - n4;
        float4 v = (isA ? (const float4*)A : (const float4*)B)[j];
        ushort4 p;
        p.x = f2bf(v.x); p.y = f2bf(v.y); p.z = f2bf(v.z); p.w = f2bf(v.w);
        *(ushort4*)((isA ? Abf : Bbf) + (size_t)j * 4) = p;
    }
}

// ---------------------------------------------------------------------------
// 2a. fused corr: 1024 persistent blocks; per tile: R2-proven GEMM ->
//     colSq RMWs -> group-counter sync -> RMW-fetch colSq -> normalize.
// ---------------------------------------------------------------------------
__global__ __launch_bounds__(256, 4) void corr_fused(const unsigned short* __restrict__ Abf,
                                                     const unsigned short* __restrict__ Bbf,
                                                     float* __restrict__ colSqG,
                                                     int* __restrict__ cnt,
                                                     float* __restrict__ out) {
    __shared__ unsigned short As[2 * 128 * 32];   // 16 KB
    __shared__ unsigned short Bs[2 * 128 * 32];   // 16 KB
    __shared__ float colSq[128];

    const int tid = threadIdx.x;
    const int srow  = tid >> 2;
    const int skcol = (tid & 3) * 8;
    const int wave = tid >> 6, lane = tid & 63;
    const int wm = (wave >> 1) * 64, wn = (wave & 1) * 64;
    const int lr = lane & 15, quad = lane >> 4, k8 = quad * 8;

    // group-major identity mapping: consecutive tiles = same (b,bx) group,
    // so a straddler group's missing members are the first tiles of the
    // next round (completed first -> minimal spin).
    for (int t = blockIdx.x; t < NTILE; t += PBLK) {
        const int g  = t / 18;        // group = (b, bx): shared denominator
        const int by = t % 18;        // member = row tile
        const int b  = g / 18;
        const int bx = g % 18;

        const unsigned short* Ab = Abf + ((size_t)b * HW2 + (size_t)by * 128) * CH;
        const unsigned short* Bb = Bbf + ((size_t)b * HW2 + (size_t)bx * 128) * CH;

        if (tid < 128) colSq[tid] = 0.0f;

        f32x4 acc[4][4];
#pragma unroll
        for (int mi = 0; mi < 4; mi++)
#pragma unroll
            for (int nj = 0; nj < 4; nj++) acc[mi][nj] = (f32x4){0.f, 0.f, 0.f, 0.f};

        for (int kt = 0; kt < CH; kt += 64) {
#pragma unroll
            for (int c = 0; c < 2; c++) {
                const int kof = kt + c * 32;
#pragma unroll
                for (int ii = 0; ii < 2; ii++) {
                    async_copy16(Ab + (size_t)(srow + ii * 64) * CH + kof + skcol,
                                 &As[c * 4096 + tid * 8 + ii * 2048]);
                    async_copy16(Bb + (size_t)(srow + ii * 64) * CH + kof + skcol,
                                 &Bs[c * 4096 + tid * 8 + ii * 2048]);
                }
            }
            __syncthreads();   // vmcnt(0) drain + barrier
#pragma unroll
            for (int c = 0; c < 2; c++) {
                bf16x8 af[4], bfr[4];
#pragma unroll
                for (int mt = 0; mt < 4; mt++)
                    af[mt] = *(const bf16x8*)&As[c * 4096 + (wm + mt * 16 + lr) * 32 + k8];
#pragma unroll
                for (int nt = 0; nt < 4; nt++)
                    bfr[nt] = *(const bf16x8*)&Bs[c * 4096 + (wn + nt * 16 + lr) * 32 + k8];
#pragma unroll
                for (int mt = 0; mt < 4; mt++)
#pragma unroll
                    for (int nt = 0; nt < 4; nt++)
                        acc[mt][nt] = __builtin_amdgcn_mfma_f32_16x16x32_bf16(
                            af[mt], bfr[nt], acc[mt][nt], 0, 0, 0);
            }
            __syncthreads();
        }

        // ---- per-column sum of squares -> LDS -> one global RMW per column
#pragma unroll
        for (int nt = 0; nt < 4; nt++) {
            float s = 0.f;
#pragma unroll
            for (int mt = 0; mt < 4; mt++) {
                f32x4 v = acc[mt][nt];
#pragma unroll
                for (int r = 0; r < 4; r++) s += v[r] * v[r];
            }
            s += __shfl_xor(s, 16);
            s += __shfl_xor(s, 32);
            if (quad == 0) atomicAdd(&colSq[wn + nt * 16 + lr], s);
        }
        __syncthreads();
        if (tid < 128)
            atomicAdd(&colSqG[(size_t)b * HW2 + bx * 128 + tid], colSq[tid]);
        // barrier: every wave drains vmcnt before s_barrier -> all 128 RMWs
        // complete at the coherence point before tid0 bumps cnt.
        __syncthreads();

        // ---- group sync: wait until all 18 row-blocks of (b,bx) contributed
        if (tid == 0) {
            __hip_atomic_fetch_add(&cnt[g], 1, __ATOMIC_ACQ_REL,
                                   __HIP_MEMORY_SCOPE_AGENT);
            while (__hip_atomic_load(&cnt[g], __ATOMIC_ACQUIRE,
                                     __HIP_MEMORY_SCOPE_AGENT) < 18)
                __builtin_amdgcn_s_sleep(8);
        }
        __syncthreads();

        // ---- fetch final colSq via RMW (+0.0f): serializes at the coherence
        // point, cannot read a stale cached line.
        if (tid < 128)
            colSq[tid] = __hip_atomic_fetch_add(
                &colSqG[(size_t)b * HW2 + bx * 128 + tid], 0.0f,
                __ATOMIC_RELAXED, __HIP_MEMORY_SCOPE_AGENT);
        __syncthreads();

        // ---- normalize from registers and write
        const size_t outBase = (size_t)b * HW2 * HW2;
#pragma unroll
        for (int nt = 0; nt < 4; nt++) {
            const int colL = wn + nt * 16 + lr;
            const int col  = bx * 128 + colL;
            const float rinv = rsqrtf(colSq[colL]);
#pragma unroll
            for (int mt = 0; mt < 4; mt++) {
                const int row0 = by * 128 + wm + mt * 16 + quad * 4;
                f32x4 v = acc[mt][nt];
#pragma unroll
                for (int r = 0; r < 4; r++)
                    out[outBase + (size_t)(row0 + r) * HW2 + col] = v[r] * rinv;
            }
        }
        __syncthreads();   // colSq LDS reuse safety before next tile's zeroing
    }
}

// ---------------------------------------------------------------------------
// 2b. fallback: R2's proven two-pass corr (no inter-block sync). Used only
//     if the occupancy tripwire reports <4 blocks/CU for corr_fused.
// ---------------------------------------------------------------------------
template <bool WRITE_OUT>
__global__ __launch_bounds__(256) void corr_pass(const unsigned short* __restrict__ Abf,
                                                 const unsigned short* __restrict__ Bbf,
                                                 float* __restrict__ colSqG,
                                                 float* __restrict__ out) {
    __shared__ unsigned short As[2 * 128 * 32];
    __shared__ unsigned short Bs[2 * 128 * 32];
    __shared__ float colSq[128];

    const int tid = threadIdx.x;
    const int lin = blockIdx.x + 18 * (blockIdx.y + 18 * blockIdx.z);
    const int b  = lin & 7;
    const int r_ = lin >> 3;
    const int bx = r_ % 18;
    const int by = r_ / 18;

    if (!WRITE_OUT && tid < 128) colSq[tid] = 0.0f;

    const unsigned short* Ab = Abf + ((size_t)b * HW2 + (size_t)by * 128) * CH;
    const unsigned short* Bb = Bbf + ((size_t)b * HW2 + (size_t)bx * 128) * CH;

    const int srow  = tid >> 2;
    const int skcol = (tid & 3) * 8;
    const int wave = tid >> 6, lane = tid & 63;
    const int wm = (wave >> 1) * 64, wn = (wave & 1) * 64;
    const int lr = lane & 15, quad = lane >> 4, k8 = quad * 8;

    f32x4 acc[4][4];
#pragma unroll
    for (int i = 0; i < 4; i++)
#pragma unroll
        for (int j = 0; j < 4; j++) acc[i][j] = (f32x4){0.f, 0.f, 0.f, 0.f};

    for (int kt = 0; kt < CH; kt += 64) {
#pragma unroll
        for (int c = 0; c < 2; c++) {
            const int kof = kt + c * 32;
#pragma unroll
            for (int i = 0; i < 2; i++) {
                async_copy16(Ab + (size_t)(srow + i * 64) * CH + kof + skcol,
                             &As[c * 4096 + tid * 8 + i * 2048]);
                async_copy16(Bb + (size_t)(srow + i * 64) * CH + kof + skcol,
                             &Bs[c * 4096 + tid * 8 + i * 2048]);
            }
        }
        __syncthreads();
#pragma unroll
        for (int c = 0; c < 2; c++) {
            bf16x8 af[4], bfr[4];
#pragma unroll
            for (int mt = 0; mt < 4; mt++)
                af[mt] = *(const bf16x8*)&As[c * 4096 + (wm + mt * 16 + lr) * 32 + k8];
#pragma unroll
            for (int nt = 0; nt < 4; nt++)
                bfr[nt] = *(const bf16x8*)&Bs[c * 4096 + (wn + nt * 16 + lr) * 32 + k8];
#pragma unroll
            for (int mt = 0; mt < 4; mt++)
#pragma unroll
                for (int nt = 0; nt < 4; nt++)
                    acc[mt][nt] = __builtin_amdgcn_mfma_f32_16x16x32_bf16(
                        af[mt], bfr[nt], acc[mt][nt], 0, 0, 0);
        }
        __syncthreads();
    }

    const int colBase = bx * 128 + wn;
    if (!WRITE_OUT) {
#pragma unroll
        for (int nt = 0; nt < 4; nt++) {
            float s = 0.f;
#pragma unroll
            for (int mt = 0; mt < 4; mt++) {
                f32x4 v = acc[mt][nt];
#pragma unroll
                for (int r = 0; r < 4; r++) s += v[r] * v[r];
            }
            s += __shfl_xor(s, 16);
            s += __shfl_xor(s, 32);
            if (quad == 0) atomicAdd(&colSq[wn + nt * 16 + lr], s);
        }
        __syncthreads();
        if (tid < 128)
            atomicAdd(&colSqG[(size_t)b * HW2 + bx * 128 + tid], colSq[tid]);
    } else {
        const size_t outBase = (size_t)b * HW2 * HW2;
#pragma unroll
        for (int nt = 0; nt < 4; nt++) {
            const int col = colBase + nt * 16 + lr;
            const float rinv = rsqrtf(colSqG[(size_t)b * HW2 + col]);
#pragma unroll
            for (int mt = 0; mt < 4; mt++) {
                const int row0 = by * 128 + wm + mt * 16 + quad * 4;
                f32x4 v = acc[mt][nt];
#pragma unroll
                for (int r = 0; r < 4; r++)
                    out[outBase + (size_t)(row0 + r) * HW2 + col] = v[r] * rinv;
            }
        }
    }
}

extern "C" void kernel_launch(void* const* d_in, const int* in_sizes, int n_in,
                              void* d_out, int out_size, void* d_ws, size_t ws_size,
                              hipStream_t stream) {
    const float* A = (const float*)d_in[0];
    const float* B = (const float*)d_in[1];
    float* out = (float*)d_out;

    unsigned short* Abf = (unsigned short*)d_ws;           // NELEM bf16
    unsigned short* Bbf = Abf + NELEM;                     // NELEM bf16
    float* colSqG = (float*)(Bbf + NELEM);                 // NB*HW2 f32
    int* cnt = (int*)(colSqG + (size_t)NB * HW2);          // NGRP ints

    // Occupancy tripwire: fused path requires 4 co-resident blocks/CU
    // (1024-block grid). launch_bounds(256,4) + 33KB LDS guarantee it;
    // the query guards against a surprise regression.
    static int occ = -1;
    if (occ < 0) {
        int n = 0;
        hipError_t e = hipOccupancyMaxActiveBlocksPerMultiprocessor(
            &n, (const void*)corr_fused, 256, 0);
        occ = (e == hipSuccess) ? n : 4;   // on query failure trust the static bound
    }

    convert_bf16<<<2048, 256, 0, stream>>>(A, B, Abf, Bbf, colSqG, cnt);

    if (occ >= 4) {
        corr_fused<<<PBLK, 256, 0, stream>>>(Abf, Bbf, colSqG, cnt, out);
    } else {
        dim3 grid(HW2 / 128, HW2 / 128, NB);   // 18 x 18 x 8
        corr_pass<false><<<grid, 256, 0, stream>>>(Abf, Bbf, colSqG, out);
        corr_pass<true><<<grid, 256, 0, stream>>>(Abf, Bbf, colSqG, out);
    }
}